// Round 6
// baseline (604.560 us; speedup 1.0000x reference)
//
#include <hip/hip_runtime.h>

// CRF forward (logZ) + Viterbi (best score + backpointers).
//
// r6 structural change: MERGED fwd+vit in ONE wave per batch. Grid (B),
// 64 threads, 1 wave/SIMD. Rationale (r5 ledger): per-batch-step wall was
// pinned at ~465 cy across LDS/DPP structures, VALU cuts and load cuts all
// null; OccupancyPercent ~12.7% (not 25%) showed the cheap fwd waves retire
// early, leaving the vit wave alone with its chain latency exposed. Merging
// makes every wave identical (no imbalance), gives each wave TWO independent
// chains (fwd ~28 VALU + vit ~75 VALU per step) whose issue hides each
// other's cross-lane latency, and halves feats loads (one load feeds both).
//
// Verified building blocks reused unchanged:
//   * lane map: t0=l&15, row=l>>4, tag i=((row&1)<<4)|t0; rows 2,3 duplicate
//     tags; srcbase rows 0,3 = sources 0-15, rows 1,2 = 16-31; rows 2,3 take
//     base via swap16; lane pair (l,l^32) merges halves via permlane32_swap.
//   * depth-2 DPP xor gather (hubs r7=xor7, r8=ror8==xor8, r15=xor15).
//   * fwd exact pow2 rescale (raw exponent bits, integer CE; no rcp/log).
//   * vit leftmost argmax: per-slot tag-bit select + OR + cross-half OR +
//     ffs (crf5-r2 verified exact leftmost-tie semantics).
//   * 2-probe wave-parallel length find over the monotone mask (r5).
// Viterbi value path bit-exact vs numpy; fwd only reorders the FMA sum.

#define SS 1024
#define BB 1024
#define TT 32
#define POFF (2 * BB)   // pointers offset in d_out (after logZ, best_score)
#define STEP (BB * TT)  // floats per time-step plane

#define DPP_QX1   0xB1   // quad_perm [1,0,3,2] : xor 1
#define DPP_QX2   0x4E   // quad_perm [2,3,0,1] : xor 2
#define DPP_QX3   0x1B   // quad_perm [3,2,1,0] : xor 3
#define DPP_RMIR  0x140  // row_mirror        : xor 15 (within 16)
#define DPP_RHMIR 0x141  // row_half_mirror   : xor 7  (within 8)
#define DPP_ROR8  0x128  // row_ror:8         : +8 mod 16 == xor 8

template <int CTRL>
static __device__ __forceinline__ float dppx(float x) {
  return __int_as_float(
      __builtin_amdgcn_update_dpp(0, __float_as_int(x), CTRL, 0xF, 0xF, false));
}

// y[l] = x[l ^ 32]  (VALU pipe; convention HW-verified crf5-crf8)
static __device__ __forceinline__ unsigned uswap32(unsigned x, bool hiHalf) {
#if __has_builtin(__builtin_amdgcn_permlane32_swap)
  auto r = __builtin_amdgcn_permlane32_swap(x, x, false, false);
  return hiHalf ? r[0] : r[1];
#else
  unsigned a = x, b = x;
  asm("s_nop 1\n\ts_nop 1\n\tv_permlane32_swap_b32 %0, %1"
      : "+v"(a), "+v"(b));
  return hiHalf ? a : b;
#endif
}
static __device__ __forceinline__ float swap32(float x, bool hiHalf) {
  return __uint_as_float(uswap32(__float_as_uint(x), hiHalf));
}

// y[l] = x[l ^ 16]  (convention HW-verified crf6-crf8)
static __device__ __forceinline__ float swap16(float x, bool hi16) {
#if __has_builtin(__builtin_amdgcn_permlane16_swap)
  auto r = __builtin_amdgcn_permlane16_swap(__float_as_uint(x),
                                            __float_as_uint(x), false, false);
  return __uint_as_float(hi16 ? r[0] : r[1]);
#else
  float a = x, b = x;
  asm("s_nop 1\n\ts_nop 1\n\tv_permlane16_swap_b32 %0, %1"
      : "+v"(a), "+v"(b));
  return hi16 ? a : b;
#endif
}

__global__ __launch_bounds__(64, 1) void crf9_kernel(
    const float* __restrict__ feats,
    const float* __restrict__ mask,
    const float* __restrict__ trans,
    float* __restrict__ out) {

  const int l   = threadIdx.x;
  const int t0  = l & 15;
  const int row = l >> 4;                      // 0..3
  const int i   = ((row & 1) << 4) | t0;       // tag (rows 2,3 duplicate 0,1)
  const int srcbase = (row == 1 || row == 2) ? 16 : 0;
  const bool hi16   = (row & 1) != 0;          // lane bit4
  const bool hiHalf = (row & 2) != 0;          // lane bit5 (rows 2,3 use z)
  const int b = blockIdx.x;

  const float* fbase = feats + (size_t)b * TT + i;   // + s*STEP per step
  const float t_stop = trans[30 * TT + i];           // trans[STOP_TAG][i]

  // Prefetch steps 0..7 (issued before the probe; independent of len).
  float fA[4], fB[4];
#pragma unroll
  for (int u = 0; u < 4; ++u) {
    fA[u] = fbase[(size_t)u * STEP];
    fB[u] = fbase[(size_t)(u + 4) * STEP];
  }

  // ---- one-time length probe over monotone mask[s][b] (r5-verified).
  int len;
  {
    float pr1 = mask[(size_t)(l << 4) * BB + b];
    unsigned long long m1 = __ballot(pr1 != 0.0f);
    unsigned long long nz = ~m1;
    int z1 = nz ? (__ffsll(nz) - 1) : 64;     // first zero probe lane
    int W = (z1 << 4) - 16;                   // window start (>= 496)
    float pr2 = mask[(size_t)(W + t0) * BB + b];
    unsigned long long m2 = __ballot(pr2 != 0.0f);
    len = W + __popcll(m2 & 0xFFFFull);
  }
  const int lim8 = len & ~7;                  // full 8-step groups
  const int rem  = len - lim8;                // 0..7 tail steps

  // ---- per-lane constants: transitions row in xor-slot order
  float eT[16], tT[16];
  unsigned tgb[16];                           // 1u << source-tag (ffs argmax)
#pragma unroll
  for (int m = 0; m < 16; ++m) {
    int j = srcbase | (t0 ^ m);
    float tv = trans[i * TT + j];
    tT[m]  = tv;
    eT[m]  = __expf(tv);                      // exp(-1e4) == 0 exactly
    tgb[m] = 1u << j;
  }

  // ---- states
  float p   = (i == 29) ? 1.0f : 0.0f;        // fwd: exp(alpha0), START=29
  int   CE  = 0;                              // fwd: exact pow2 exponent sum
  float q0f = 1.0f;                           // fwd: lagged p[lane0]
  float sc  = (i == 29) ? 0.0f : -10000.0f;   // vit state
  float* outp = out + POFF + (size_t)b * TT + i;

  // ---- merged step: viterbi first (store ptr), then forward; both use fv.
  auto step = [&](float fv, int s) {
    // ======== viterbi ========
    float zv = swap16(sc, hi16);
    float xv = hiHalf ? zv : sc;
    float v7  = dppx<DPP_RHMIR>(xv);
    float v8  = dppx<DPP_ROR8>(xv);
    float v15 = dppx<DPP_RMIR>(xv);
    float vv[16];
    vv[0]  = xv + tT[0];
    vv[1]  = dppx<DPP_QX1>(xv) + tT[1];
    vv[2]  = dppx<DPP_QX2>(xv) + tT[2];
    vv[3]  = dppx<DPP_QX3>(xv) + tT[3];
    vv[4]  = dppx<DPP_QX3>(v7) + tT[4];
    vv[5]  = dppx<DPP_QX2>(v7) + tT[5];
    vv[6]  = dppx<DPP_QX1>(v7) + tT[6];
    vv[7]  = v7 + tT[7];
    vv[8]  = v8 + tT[8];
    vv[9]  = dppx<DPP_QX1>(v8) + tT[9];
    vv[10] = dppx<DPP_QX2>(v8) + tT[10];
    vv[11] = dppx<DPP_QX3>(v8) + tT[11];
    vv[12] = dppx<DPP_QX3>(v15) + tT[12];
    vv[13] = dppx<DPP_QX2>(v15) + tT[13];
    vv[14] = dppx<DPP_QX1>(v15) + tT[14];
    vv[15] = v15 + tT[15];
    // exact max (3-ary nesting -> v_max3_f32)
    float g0 = fmaxf(fmaxf(vv[0], vv[1]), vv[2]);
    float g1 = fmaxf(fmaxf(vv[3], vv[4]), vv[5]);
    float g2 = fmaxf(fmaxf(vv[6], vv[7]), vv[8]);
    float g3 = fmaxf(fmaxf(vv[9], vv[10]), vv[11]);
    float g4 = fmaxf(fmaxf(vv[12], vv[13]), vv[14]);
    float h0 = fmaxf(fmaxf(g0, g1), g2);
    float h1 = fmaxf(fmaxf(g3, g4), vv[15]);
    float mxp = fmaxf(h0, h1);
    float mx  = fmaxf(mxp, swap32(mxp, hiHalf));  // global over 32 sources
    // leftmost argmax: OR of tag-bits among exact-max matches, then ffs
    unsigned msk = 0u;
#pragma unroll
    for (int m = 0; m < 16; ++m) msk |= (vv[m] == mx) ? tgb[m] : 0u;
    msk |= uswap32(msk, hiHalf);
    int ptr = __ffs(msk) - 1;
    if (l < 32) outp[(size_t)s * STEP] = (float)ptr;

    // ======== forward ========
    float ef = __expf(fv);                    // off-chain (load-dep only)
    int Eb = (int)((__float_as_uint(q0f) >> 23) & 0xFFu);
    float scl = __uint_as_float((unsigned)(254 - Eb) << 23);  // 2^-(Eb-127)
    float efs = ef * scl;
    float zp = swap16(p, hi16);
    float xp = hiHalf ? zp : p;
    float r7  = dppx<DPP_RHMIR>(xp);
    float r8  = dppx<DPP_ROR8>(xp);
    float r15 = dppx<DPP_RMIR>(xp);
    float a0 = eT[0] * xp;
    float a1 = eT[1] * dppx<DPP_QX1>(xp);
    float a2 = eT[2] * dppx<DPP_QX2>(xp);
    float a3 = eT[3] * dppx<DPP_QX3>(xp);
    a0 = fmaf(dppx<DPP_QX3>(r7),  eT[4],  a0);
    a1 = fmaf(dppx<DPP_QX2>(r7),  eT[5],  a1);
    a2 = fmaf(dppx<DPP_QX1>(r7),  eT[6],  a2);
    a3 = fmaf(r7,                 eT[7],  a3);
    a0 = fmaf(r8,                 eT[8],  a0);
    a1 = fmaf(dppx<DPP_QX1>(r8),  eT[9],  a1);
    a2 = fmaf(dppx<DPP_QX2>(r8),  eT[10], a2);
    a3 = fmaf(dppx<DPP_QX3>(r8),  eT[11], a3);
    a0 = fmaf(dppx<DPP_QX3>(r15), eT[12], a0);
    a1 = fmaf(dppx<DPP_QX2>(r15), eT[13], a1);
    a2 = fmaf(dppx<DPP_QX1>(r15), eT[14], a2);
    a3 = fmaf(r15,                eT[15], a3);
    float Dp = (a0 + a1) + (a2 + a3);         // partial over 16 sources
    float Df = Dp + swap32(Dp, hiHalf);       // + complementary partial
    p = Df * efs;
    CE += Eb - 127;                           // integer, exact
    q0f = __uint_as_float(
        (unsigned)__builtin_amdgcn_readfirstlane((int)__float_as_uint(p)));

    // ======== vit state update (bit-exact vs numpy) ========
    sc = mx + fv;
  };

#pragma unroll 1
  for (int s = 0; s < lim8; s += 8) {
    step(fA[0], s);     step(fA[1], s + 1);
    step(fA[2], s + 2); step(fA[3], s + 3);
#pragma unroll
    for (int u = 0; u < 4; ++u)
      fA[u] = fbase[(size_t)((s + 8 + u) & (SS - 1)) * STEP];
    step(fB[0], s + 4); step(fB[1], s + 5);
    step(fB[2], s + 6); step(fB[3], s + 7);
#pragma unroll
    for (int u = 0; u < 4; ++u)
      fB[u] = fbase[(size_t)((s + 12 + u) & (SS - 1)) * STEP];
  }
  // tail: rem in 0..7, data already prefetched in fA/fB (steps lim8..+7)
  if (rem > 0) step(fA[0], lim8 + 0);
  if (rem > 1) step(fA[1], lim8 + 1);
  if (rem > 2) step(fA[2], lim8 + 2);
  if (rem > 3) step(fA[3], lim8 + 3);
  if (rem > 4) step(fB[0], lim8 + 4);
  if (rem > 5) step(fB[1], lim8 + 5);
  if (rem > 6) step(fB[2], lim8 + 6);

  // ======== viterbi frozen tail: scores constant -> one ptr row ========
  {
    float zv = swap16(sc, hi16);
    float xv = hiHalf ? zv : sc;
    float v7  = dppx<DPP_RHMIR>(xv);
    float v8  = dppx<DPP_ROR8>(xv);
    float v15 = dppx<DPP_RMIR>(xv);
    float vv[16];
    vv[0]  = xv + tT[0];
    vv[1]  = dppx<DPP_QX1>(xv) + tT[1];
    vv[2]  = dppx<DPP_QX2>(xv) + tT[2];
    vv[3]  = dppx<DPP_QX3>(xv) + tT[3];
    vv[4]  = dppx<DPP_QX3>(v7) + tT[4];
    vv[5]  = dppx<DPP_QX2>(v7) + tT[5];
    vv[6]  = dppx<DPP_QX1>(v7) + tT[6];
    vv[7]  = v7 + tT[7];
    vv[8]  = v8 + tT[8];
    vv[9]  = dppx<DPP_QX1>(v8) + tT[9];
    vv[10] = dppx<DPP_QX2>(v8) + tT[10];
    vv[11] = dppx<DPP_QX3>(v8) + tT[11];
    vv[12] = dppx<DPP_QX3>(v15) + tT[12];
    vv[13] = dppx<DPP_QX2>(v15) + tT[13];
    vv[14] = dppx<DPP_QX1>(v15) + tT[14];
    vv[15] = v15 + tT[15];
    float g0 = fmaxf(fmaxf(vv[0], vv[1]), vv[2]);
    float g1 = fmaxf(fmaxf(vv[3], vv[4]), vv[5]);
    float g2 = fmaxf(fmaxf(vv[6], vv[7]), vv[8]);
    float g3 = fmaxf(fmaxf(vv[9], vv[10]), vv[11]);
    float g4 = fmaxf(fmaxf(vv[12], vv[13]), vv[14]);
    float h0 = fmaxf(fmaxf(g0, g1), g2);
    float h1 = fmaxf(fmaxf(g3, g4), vv[15]);
    float mxp = fmaxf(h0, h1);
    float mx  = fmaxf(mxp, swap32(mxp, hiHalf));
    unsigned msk = 0u;
#pragma unroll
    for (int m = 0; m < 16; ++m) msk |= (vv[m] == mx) ? tgb[m] : 0u;
    msk |= uswap32(msk, hiHalf);
    float tj = (float)(__ffs(msk) - 1);
#pragma unroll 1
    for (int s2 = len; s2 < SS; ++s2)
      if (l < 32) outp[(size_t)s2 * STEP] = tj;
  }

  // ======== epilogues ========
  {
    // fwd logZ
    float alpha = (float)CE * 0.693147180559945f + __logf(p);  // p==0 -> -inf
    float v = alpha + t_stop;
    float M2 = v;
    M2 = fmaxf(M2, __shfl_xor(M2, 1, 64));
    M2 = fmaxf(M2, __shfl_xor(M2, 2, 64));
    M2 = fmaxf(M2, __shfl_xor(M2, 4, 64));
    M2 = fmaxf(M2, __shfl_xor(M2, 8, 64));
    M2 = fmaxf(M2, __shfl_xor(M2, 16, 64));
    float e = __expf(v - M2);
    e += __shfl_xor(e, 1, 64);
    e += __shfl_xor(e, 2, 64);
    e += __shfl_xor(e, 4, 64);
    e += __shfl_xor(e, 8, 64);
    e += __shfl_xor(e, 16, 64);
    if (l == 0) out[b] = M2 + __logf(e);

    // vit best_score
    float w = sc + t_stop;
    w = fmaxf(w, __shfl_xor(w, 1, 64));
    w = fmaxf(w, __shfl_xor(w, 2, 64));
    w = fmaxf(w, __shfl_xor(w, 4, 64));
    w = fmaxf(w, __shfl_xor(w, 8, 64));
    w = fmaxf(w, __shfl_xor(w, 16, 64));
    if (l == 0) out[BB + b] = w;
  }
}

extern "C" void kernel_launch(void* const* d_in, const int* in_sizes, int n_in,
                              void* d_out, int out_size, void* d_ws, size_t ws_size,
                              hipStream_t stream) {
  const float* feats = (const float*)d_in[0];
  const float* msk   = (const float*)d_in[1];
  const float* trans = (const float*)d_in[2];
  float* out = (float*)d_out;
  (void)in_sizes; (void)n_in; (void)out_size; (void)d_ws; (void)ws_size;
  crf9_kernel<<<dim3(BB), dim3(64), 0, stream>>>(feats, msk, trans, out);
}

// Round 7
// 546.408 us; speedup vs baseline: 1.1064x; 1.1064x over previous
//
#include <hip/hip_runtime.h>

// CRF forward (logZ) + Viterbi (best score + backpointers).
//
// Structure = crf8 (r5, 397 us best): grid (B,2), one batch per wave, one
// role per wave (blockIdx.y), 2048 waves = 2/SIMD. Lane map (HW-verified):
// t0=l&15, row=l>>4, tag i=((row&1)<<4)|t0; rows 2,3 duplicate tags;
// srcbase rows 0,3 = sources 0-15, rows 1,2 = 16-31; rows 2,3 take base via
// permlane16_swap; lane pair (l,l^32) merges halves via permlane32_swap.
// Depth-2 DPP xor gather; exact pow2 rescale; bitmask+ffs leftmost argmax;
// 2-probe length find; no mask in loop.
//
// r7 single change: REGISTER-PIN the loop-invariant per-lane constants
// (eT/tT/tgb/t_stop) with asm volatile("" : "+v"(x)) after computing them.
// Ledger r3-r6: ~930-1060 cy/wave-step invariant to gather style, -30%
// VALU, -47MB mask traffic, -50% feats loads; VALUBusy matches two waves
// stalling INDEPENDENTLY ~70% each. VGPR_Count=40-48 while live constant
// state is 60-90 values => compiler is REMATERIALIZING constants in-loop
// (per-step trans reloads + expf), putting L1/TRANS latency on the chain.
// The pin makes each value's origin opaque => cannot remat => must stay in
// a VGPR (launch_bounds(64,2) caps at 256, we need ~100). fA/fB NOT pinned
// (a pin reads the reg -> would force waitcnt at pin site and serialize
// the prefetch).
//
// Viterbi value path bit-exact vs numpy; fwd only reorders the FMA sum.

#define SS 1024
#define BB 1024
#define TT 32
#define POFF (2 * BB)   // pointers offset in d_out (after logZ, best_score)
#define STEP (BB * TT)  // floats per time-step plane

#define DPP_QX1   0xB1   // quad_perm [1,0,3,2] : xor 1
#define DPP_QX2   0x4E   // quad_perm [2,3,0,1] : xor 2
#define DPP_QX3   0x1B   // quad_perm [3,2,1,0] : xor 3
#define DPP_RMIR  0x140  // row_mirror        : xor 15 (within 16)
#define DPP_RHMIR 0x141  // row_half_mirror   : xor 7  (within 8)
#define DPP_ROR8  0x128  // row_ror:8         : +8 mod 16 == xor 8

#define PINF(x) asm volatile("" : "+v"(x))   // keep in VGPR, forbid remat

template <int CTRL>
static __device__ __forceinline__ float dppx(float x) {
  return __int_as_float(
      __builtin_amdgcn_update_dpp(0, __float_as_int(x), CTRL, 0xF, 0xF, false));
}

// y[l] = x[l ^ 32]  (VALU pipe; convention HW-verified crf5-crf9)
static __device__ __forceinline__ unsigned uswap32(unsigned x, bool hiHalf) {
#if __has_builtin(__builtin_amdgcn_permlane32_swap)
  auto r = __builtin_amdgcn_permlane32_swap(x, x, false, false);
  return hiHalf ? r[0] : r[1];
#else
  unsigned a = x, b = x;
  asm("s_nop 1\n\ts_nop 1\n\tv_permlane32_swap_b32 %0, %1"
      : "+v"(a), "+v"(b));
  return hiHalf ? a : b;
#endif
}
static __device__ __forceinline__ float swap32(float x, bool hiHalf) {
  return __uint_as_float(uswap32(__float_as_uint(x), hiHalf));
}

// y[l] = x[l ^ 16]  (convention HW-verified crf6-crf9)
static __device__ __forceinline__ float swap16(float x, bool hi16) {
#if __has_builtin(__builtin_amdgcn_permlane16_swap)
  auto r = __builtin_amdgcn_permlane16_swap(__float_as_uint(x),
                                            __float_as_uint(x), false, false);
  return __uint_as_float(hi16 ? r[0] : r[1]);
#else
  float a = x, b = x;
  asm("s_nop 1\n\ts_nop 1\n\tv_permlane16_swap_b32 %0, %1"
      : "+v"(a), "+v"(b));
  return hi16 ? a : b;
#endif
}

__global__ __launch_bounds__(64, 2) void crf10_kernel(
    const float* __restrict__ feats,
    const float* __restrict__ mask,
    const float* __restrict__ trans,
    float* __restrict__ out) {

  const int l   = threadIdx.x;
  const int t0  = l & 15;
  const int row = l >> 4;                      // 0..3
  const int i   = ((row & 1) << 4) | t0;       // tag (rows 2,3 duplicate 0,1)
  const int srcbase = (row == 1 || row == 2) ? 16 : 0;
  const bool hi16   = (row & 1) != 0;          // lane bit4
  const bool hiHalf = (row & 2) != 0;          // lane bit5 (rows 2,3 use z)
  const int b = blockIdx.x;

  const float* fbase = feats + (size_t)b * TT + i;   // + s*STEP per step
  float t_stop = trans[30 * TT + i];           // trans[STOP_TAG][i]
  PINF(t_stop);

  // Prefetch steps 0..7 (issued before the probe; independent of len).
  float fA[4], fB[4];
#pragma unroll
  for (int u = 0; u < 4; ++u) {
    fA[u] = fbase[(size_t)u * STEP];
    fB[u] = fbase[(size_t)(u + 4) * STEP];
  }

  // ---- one-time length probe over monotone mask[s][b] (r5-verified).
  int len;
  {
    float pr1 = mask[(size_t)(l << 4) * BB + b];
    unsigned long long m1 = __ballot(pr1 != 0.0f);
    unsigned long long nz = ~m1;
    int z1 = nz ? (__ffsll(nz) - 1) : 64;     // first zero probe lane
    int W = (z1 << 4) - 16;                   // window start (>= 496)
    float pr2 = mask[(size_t)(W + t0) * BB + b];
    unsigned long long m2 = __ballot(pr2 != 0.0f);
    len = W + __popcll(m2 & 0xFFFFull);
  }
  const int lim8 = len & ~7;                  // full 8-step groups
  const int rem  = len - lim8;                // 0..7 tail steps

  if (blockIdx.y == 0) {
    // ======================= forward (logZ) =======================
    float eT[16];
#pragma unroll
    for (int m = 0; m < 16; ++m) {
      eT[m] = __expf(trans[i * TT + (srcbase | (t0 ^ m))]);  // exp(-1e4)==0
      PINF(eT[m]);                            // VGPR-resident, no remat
    }

    float p   = (i == 29) ? 1.0f : 0.0f;   // exp(alpha0), START_TAG = 29
    int   CE  = 0;                         // exact pow2 rescale exponent sum
    float q0f = 1.0f;                      // lagged p[lane0] (any >0 valid)

    auto fstep = [&](float fv) {
      float ef = __expf(fv);               // off-chain (load-dependent only)
      int Eb = (int)((__float_as_uint(q0f) >> 23) & 0xFFu);
      float scl = __uint_as_float((unsigned)(254 - Eb) << 23);  // 2^-(Eb-127)
      float efs = ef * scl;
      float z = swap16(p, hi16);           // rows 2,3 source base
      float x = hiHalf ? z : p;
      float r7  = dppx<DPP_RHMIR>(x);      // depth-2 hubs
      float r8  = dppx<DPP_ROR8>(x);
      float r15 = dppx<DPP_RMIR>(x);
      float a0 = eT[0] * x;
      float a1 = eT[1] * dppx<DPP_QX1>(x);
      float a2 = eT[2] * dppx<DPP_QX2>(x);
      float a3 = eT[3] * dppx<DPP_QX3>(x);
      a0 = fmaf(dppx<DPP_QX3>(r7),  eT[4],  a0);
      a1 = fmaf(dppx<DPP_QX2>(r7),  eT[5],  a1);
      a2 = fmaf(dppx<DPP_QX1>(r7),  eT[6],  a2);
      a3 = fmaf(r7,                 eT[7],  a3);
      a0 = fmaf(r8,                 eT[8],  a0);
      a1 = fmaf(dppx<DPP_QX1>(r8),  eT[9],  a1);
      a2 = fmaf(dppx<DPP_QX2>(r8),  eT[10], a2);
      a3 = fmaf(dppx<DPP_QX3>(r8),  eT[11], a3);
      a0 = fmaf(dppx<DPP_QX3>(r15), eT[12], a0);
      a1 = fmaf(dppx<DPP_QX2>(r15), eT[13], a1);
      a2 = fmaf(dppx<DPP_QX1>(r15), eT[14], a2);
      a3 = fmaf(r15,                eT[15], a3);
      float Dp = (a0 + a1) + (a2 + a3);    // partial over this lane's 16 srcs
      float Df = Dp + swap32(Dp, hiHalf);  // + complementary partial (l^32)
      p = Df * efs;
      CE += Eb - 127;                      // integer, exact
      q0f = __uint_as_float(
          (unsigned)__builtin_amdgcn_readfirstlane((int)__float_as_uint(p)));
    };

#pragma unroll 1
    for (int s = 0; s < lim8; s += 8) {
      fstep(fA[0]); fstep(fA[1]); fstep(fA[2]); fstep(fA[3]);
#pragma unroll
      for (int u = 0; u < 4; ++u)
        fA[u] = fbase[(size_t)((s + 8 + u) & (SS - 1)) * STEP];
      fstep(fB[0]); fstep(fB[1]); fstep(fB[2]); fstep(fB[3]);
#pragma unroll
      for (int u = 0; u < 4; ++u)
        fB[u] = fbase[(size_t)((s + 12 + u) & (SS - 1)) * STEP];
    }
    // tail: rem in 0..7, data already prefetched in fA/fB (steps lim8..+7)
    if (rem > 0) fstep(fA[0]);
    if (rem > 1) fstep(fA[1]);
    if (rem > 2) fstep(fA[2]);
    if (rem > 3) fstep(fA[3]);
    if (rem > 4) fstep(fB[0]);
    if (rem > 5) fstep(fB[1]);
    if (rem > 6) fstep(fB[2]);
    {
      float alpha = (float)CE * 0.693147180559945f + __logf(p);  // p==0 -> -inf
      float v = alpha + t_stop;
      // lanes 0-31 hold all 32 tags (dup in 32-63): xor set {1,2,4,8,16}
      float M2 = v;
      M2 = fmaxf(M2, __shfl_xor(M2, 1, 64));
      M2 = fmaxf(M2, __shfl_xor(M2, 2, 64));
      M2 = fmaxf(M2, __shfl_xor(M2, 4, 64));
      M2 = fmaxf(M2, __shfl_xor(M2, 8, 64));
      M2 = fmaxf(M2, __shfl_xor(M2, 16, 64));
      float e = __expf(v - M2);
      e += __shfl_xor(e, 1, 64);
      e += __shfl_xor(e, 2, 64);
      e += __shfl_xor(e, 4, 64);
      e += __shfl_xor(e, 8, 64);
      e += __shfl_xor(e, 16, 64);
      if (l == 0) out[b] = M2 + __logf(e);
    }
    return;
  }

  // ========================= viterbi =========================
  {
    float tT[16];
    unsigned tgb[16];                         // 1u << source-tag (ffs argmax)
#pragma unroll
    for (int m = 0; m < 16; ++m) {
      int j = srcbase | (t0 ^ m);
      tT[m]  = trans[i * TT + j];
      tgb[m] = 1u << j;
      PINF(tT[m]);                            // VGPR-resident, no remat
      PINF(tgb[m]);
    }

    float sc = (i == 29) ? 0.0f : -10000.0f;
    float* outp = out + POFF + (size_t)b * TT + i;

    auto vstep = [&](float& best, int& ptr) {
      float z = swap16(sc, hi16);
      float x = hiHalf ? z : sc;
      float r7  = dppx<DPP_RHMIR>(x);
      float r8  = dppx<DPP_ROR8>(x);
      float r15 = dppx<DPP_RMIR>(x);
      float vv[16];
      vv[0]  = x + tT[0];
      vv[1]  = dppx<DPP_QX1>(x) + tT[1];
      vv[2]  = dppx<DPP_QX2>(x) + tT[2];
      vv[3]  = dppx<DPP_QX3>(x) + tT[3];
      vv[4]  = dppx<DPP_QX3>(r7) + tT[4];
      vv[5]  = dppx<DPP_QX2>(r7) + tT[5];
      vv[6]  = dppx<DPP_QX1>(r7) + tT[6];
      vv[7]  = r7 + tT[7];
      vv[8]  = r8 + tT[8];
      vv[9]  = dppx<DPP_QX1>(r8) + tT[9];
      vv[10] = dppx<DPP_QX2>(r8) + tT[10];
      vv[11] = dppx<DPP_QX3>(r8) + tT[11];
      vv[12] = dppx<DPP_QX3>(r15) + tT[12];
      vv[13] = dppx<DPP_QX2>(r15) + tT[13];
      vv[14] = dppx<DPP_QX1>(r15) + tT[14];
      vv[15] = r15 + tT[15];
      // exact max (3-ary nesting -> v_max3_f32)
      float g0 = fmaxf(fmaxf(vv[0], vv[1]), vv[2]);
      float g1 = fmaxf(fmaxf(vv[3], vv[4]), vv[5]);
      float g2 = fmaxf(fmaxf(vv[6], vv[7]), vv[8]);
      float g3 = fmaxf(fmaxf(vv[9], vv[10]), vv[11]);
      float g4 = fmaxf(fmaxf(vv[12], vv[13]), vv[14]);
      float h0 = fmaxf(fmaxf(g0, g1), g2);
      float h1 = fmaxf(fmaxf(g3, g4), vv[15]);
      float mxp = fmaxf(h0, h1);
      float mx  = fmaxf(mxp, swap32(mxp, hiHalf));  // global over 32 sources
      // leftmost argmax: OR of tag-bits among exact-max matches, then ffs
      unsigned msk = 0u;
#pragma unroll
      for (int m = 0; m < 16; ++m) msk |= (vv[m] == mx) ? tgb[m] : 0u;
      msk |= uswap32(msk, hiHalf);
      best = mx;
      ptr  = __ffs(msk) - 1;
    };

#pragma unroll 1
    for (int s = 0; s < lim8; s += 8) {
#pragma unroll
      for (int u2 = 0; u2 < 4; ++u2) {
        float best; int ptr;
        vstep(best, ptr);
        if (l < 32) outp[(size_t)(s + u2) * STEP] = (float)ptr;
        sc = best + fA[u2];                 // bit-exact vs numpy
      }
#pragma unroll
      for (int u2 = 0; u2 < 4; ++u2)
        fA[u2] = fbase[(size_t)((s + 8 + u2) & (SS - 1)) * STEP];
#pragma unroll
      for (int u2 = 0; u2 < 4; ++u2) {
        float best; int ptr;
        vstep(best, ptr);
        if (l < 32) outp[(size_t)(s + 4 + u2) * STEP] = (float)ptr;
        sc = best + fB[u2];
      }
#pragma unroll
      for (int u2 = 0; u2 < 4; ++u2)
        fB[u2] = fbase[(size_t)((s + 12 + u2) & (SS - 1)) * STEP];
    }
    // tail steps lim8..len-1 (data already in fA/fB)
    {
      float tf[7] = {fA[0], fA[1], fA[2], fA[3], fB[0], fB[1], fB[2]};
#pragma unroll 1
      for (int k2 = 0; k2 < rem; ++k2) {
        float best; int ptr;
        vstep(best, ptr);
        if (l < 32) outp[(size_t)(lim8 + k2) * STEP] = (float)ptr;
        sc = best + tf[k2];
      }
    }
    {
      // frozen scores -> constant ptr rows: compute once, store-only loop
      float tb; int tp;
      vstep(tb, tp);
      float tj = (float)tp;
#pragma unroll 1
      for (int s2 = len; s2 < SS; ++s2)
        if (l < 32) outp[(size_t)s2 * STEP] = tj;

      float w = sc + t_stop;
      w = fmaxf(w, __shfl_xor(w, 1, 64));
      w = fmaxf(w, __shfl_xor(w, 2, 64));
      w = fmaxf(w, __shfl_xor(w, 4, 64));
      w = fmaxf(w, __shfl_xor(w, 8, 64));
      w = fmaxf(w, __shfl_xor(w, 16, 64));
      if (l == 0) out[BB + b] = w;
    }
  }
}

extern "C" void kernel_launch(void* const* d_in, const int* in_sizes, int n_in,
                              void* d_out, int out_size, void* d_ws, size_t ws_size,
                              hipStream_t stream) {
  const float* feats = (const float*)d_in[0];
  const float* msk   = (const float*)d_in[1];
  const float* trans = (const float*)d_in[2];
  float* out = (float*)d_out;
  (void)in_sizes; (void)n_in; (void)out_size; (void)d_ws; (void)ws_size;
  crf10_kernel<<<dim3(BB, 2), dim3(64), 0, stream>>>(feats, msk, trans, out);
}

// Round 8
// 539.706 us; speedup vs baseline: 1.1202x; 1.0124x over previous
//
#include <hip/hip_runtime.h>

// CRF forward (logZ) + Viterbi (best score + backpointers).
//
// r8 single change vs crf10: FUSE the two roles into ONE 128-thread block
// (2 waves): wave 0 = forward, wave 1 = viterbi, same batch b = blockIdx.x.
// Rationale: grid (B,2) linearizes x-major -> all 1024 fwd blocks dispatch
// first, fill all 1024 SIMDs, and vit only backfills as fwd retires.
// Measured OccupancyPercent ~12.8% == 1 wave/SIMD time-average: the phases
// ran SEQUENTIALLY, each latency-exposed. Waves of one block are guaranteed
// co-resident (4 blocks/CU = 2 waves/SIMD from t=0), lifetimes matched
// (same len), and same-batch pairing shares feats lines in L1/L2.
//
// Per-step math is crf10's, byte-for-byte (all HW-verified):
//   lane map t0=l&15, row=l>>4, tag i=((row&1)<<4)|t0; rows 2,3 duplicate
//   tags; srcbase rows 0,3 = sources 0-15, rows 1,2 = 16-31; rows 2,3 take
//   base via permlane16_swap; lane pair (l,l^32) merges halves via
//   permlane32_swap; depth-2 DPP xor gather (hubs xor7 / ror8==xor8 /
//   xor15) with leaf permutes single-use (fuse to v_add/v_fmac_dpp);
//   fwd exact pow2 rescale (raw exponent, integer CE; no rcp/log in loop);
//   vit leftmost argmax = OR of tag-bits among exact-max matches + ffs;
//   2-probe wave-parallel length find; no mask loads in the loop.
// Viterbi value path bit-exact vs numpy; fwd only reorders the FMA sum.

#define SS 1024
#define BB 1024
#define TT 32
#define POFF (2 * BB)   // pointers offset in d_out (after logZ, best_score)
#define STEP (BB * TT)  // floats per time-step plane

#define DPP_QX1   0xB1   // quad_perm [1,0,3,2] : xor 1
#define DPP_QX2   0x4E   // quad_perm [2,3,0,1] : xor 2
#define DPP_QX3   0x1B   // quad_perm [3,2,1,0] : xor 3
#define DPP_RMIR  0x140  // row_mirror        : xor 15 (within 16)
#define DPP_RHMIR 0x141  // row_half_mirror   : xor 7  (within 8)
#define DPP_ROR8  0x128  // row_ror:8         : +8 mod 16 == xor 8

template <int CTRL>
static __device__ __forceinline__ float dppx(float x) {
  return __int_as_float(
      __builtin_amdgcn_update_dpp(0, __float_as_int(x), CTRL, 0xF, 0xF, false));
}

// y[l] = x[l ^ 32]  (VALU pipe; convention HW-verified crf5-crf10)
static __device__ __forceinline__ unsigned uswap32(unsigned x, bool hiHalf) {
#if __has_builtin(__builtin_amdgcn_permlane32_swap)
  auto r = __builtin_amdgcn_permlane32_swap(x, x, false, false);
  return hiHalf ? r[0] : r[1];
#else
  unsigned a = x, b = x;
  asm("s_nop 1\n\ts_nop 1\n\tv_permlane32_swap_b32 %0, %1"
      : "+v"(a), "+v"(b));
  return hiHalf ? a : b;
#endif
}
static __device__ __forceinline__ float swap32(float x, bool hiHalf) {
  return __uint_as_float(uswap32(__float_as_uint(x), hiHalf));
}

// y[l] = x[l ^ 16]  (convention HW-verified crf6-crf10)
static __device__ __forceinline__ float swap16(float x, bool hi16) {
#if __has_builtin(__builtin_amdgcn_permlane16_swap)
  auto r = __builtin_amdgcn_permlane16_swap(__float_as_uint(x),
                                            __float_as_uint(x), false, false);
  return __uint_as_float(hi16 ? r[0] : r[1]);
#else
  float a = x, b = x;
  asm("s_nop 1\n\ts_nop 1\n\tv_permlane16_swap_b32 %0, %1"
      : "+v"(a), "+v"(b));
  return hi16 ? a : b;
#endif
}

__global__ __launch_bounds__(128, 2) void crf11_kernel(
    const float* __restrict__ feats,
    const float* __restrict__ mask,
    const float* __restrict__ trans,
    float* __restrict__ out) {

  const int tid = threadIdx.x;
  const int wv  = tid >> 6;                    // 0 = forward, 1 = viterbi
  const int l   = tid & 63;                    // lane within wave
  const int t0  = l & 15;
  const int row = l >> 4;                      // 0..3
  const int i   = ((row & 1) << 4) | t0;       // tag (rows 2,3 duplicate 0,1)
  const int srcbase = (row == 1 || row == 2) ? 16 : 0;
  const bool hi16   = (row & 1) != 0;          // lane bit4
  const bool hiHalf = (row & 2) != 0;          // lane bit5 (rows 2,3 use z)
  const int b = blockIdx.x;

  const float* fbase = feats + (size_t)b * TT + i;   // + s*STEP per step
  const float t_stop = trans[30 * TT + i];           // trans[STOP_TAG][i]

  // Prefetch steps 0..7 (issued before the probe; independent of len).
  float fA[4], fB[4];
#pragma unroll
  for (int u = 0; u < 4; ++u) {
    fA[u] = fbase[(size_t)u * STEP];
    fB[u] = fbase[(size_t)(u + 4) * STEP];
  }

  // ---- one-time length probe over monotone mask[s][b] (r5-verified).
  int len;
  {
    float pr1 = mask[(size_t)(l << 4) * BB + b];
    unsigned long long m1 = __ballot(pr1 != 0.0f);
    unsigned long long nz = ~m1;
    int z1 = nz ? (__ffsll(nz) - 1) : 64;     // first zero probe lane
    int W = (z1 << 4) - 16;                   // window start (>= 496)
    float pr2 = mask[(size_t)(W + t0) * BB + b];
    unsigned long long m2 = __ballot(pr2 != 0.0f);
    len = W + __popcll(m2 & 0xFFFFull);
  }
  const int lim8 = len & ~7;                  // full 8-step groups
  const int rem  = len - lim8;                // 0..7 tail steps

  if (wv == 0) {
    // ======================= forward (logZ) =======================
    float eT[16];
#pragma unroll
    for (int m = 0; m < 16; ++m)
      eT[m] = __expf(trans[i * TT + (srcbase | (t0 ^ m))]);  // exp(-1e4)==0

    float p   = (i == 29) ? 1.0f : 0.0f;   // exp(alpha0), START_TAG = 29
    int   CE  = 0;                         // exact pow2 rescale exponent sum
    float q0f = 1.0f;                      // lagged p[lane0] (any >0 valid)

    auto fstep = [&](float fv) {
      float ef = __expf(fv);               // off-chain (load-dependent only)
      int Eb = (int)((__float_as_uint(q0f) >> 23) & 0xFFu);
      float scl = __uint_as_float((unsigned)(254 - Eb) << 23);  // 2^-(Eb-127)
      float efs = ef * scl;
      float z = swap16(p, hi16);           // rows 2,3 source base
      float x = hiHalf ? z : p;
      float r7  = dppx<DPP_RHMIR>(x);      // depth-2 hubs
      float r8  = dppx<DPP_ROR8>(x);
      float r15 = dppx<DPP_RMIR>(x);
      float a0 = eT[0] * x;
      float a1 = eT[1] * dppx<DPP_QX1>(x);
      float a2 = eT[2] * dppx<DPP_QX2>(x);
      float a3 = eT[3] * dppx<DPP_QX3>(x);
      a0 = fmaf(dppx<DPP_QX3>(r7),  eT[4],  a0);
      a1 = fmaf(dppx<DPP_QX2>(r7),  eT[5],  a1);
      a2 = fmaf(dppx<DPP_QX1>(r7),  eT[6],  a2);
      a3 = fmaf(r7,                 eT[7],  a3);
      a0 = fmaf(r8,                 eT[8],  a0);
      a1 = fmaf(dppx<DPP_QX1>(r8),  eT[9],  a1);
      a2 = fmaf(dppx<DPP_QX2>(r8),  eT[10], a2);
      a3 = fmaf(dppx<DPP_QX3>(r8),  eT[11], a3);
      a0 = fmaf(dppx<DPP_QX3>(r15), eT[12], a0);
      a1 = fmaf(dppx<DPP_QX2>(r15), eT[13], a1);
      a2 = fmaf(dppx<DPP_QX1>(r15), eT[14], a2);
      a3 = fmaf(r15,                eT[15], a3);
      float Dp = (a0 + a1) + (a2 + a3);    // partial over this lane's 16 srcs
      float Df = Dp + swap32(Dp, hiHalf);  // + complementary partial (l^32)
      p = Df * efs;
      CE += Eb - 127;                      // integer, exact
      q0f = __uint_as_float(
          (unsigned)__builtin_amdgcn_readfirstlane((int)__float_as_uint(p)));
    };

#pragma unroll 1
    for (int s = 0; s < lim8; s += 8) {
      fstep(fA[0]); fstep(fA[1]); fstep(fA[2]); fstep(fA[3]);
#pragma unroll
      for (int u = 0; u < 4; ++u)
        fA[u] = fbase[(size_t)((s + 8 + u) & (SS - 1)) * STEP];
      fstep(fB[0]); fstep(fB[1]); fstep(fB[2]); fstep(fB[3]);
#pragma unroll
      for (int u = 0; u < 4; ++u)
        fB[u] = fbase[(size_t)((s + 12 + u) & (SS - 1)) * STEP];
    }
    // tail: rem in 0..7, data already prefetched in fA/fB (steps lim8..+7)
    if (rem > 0) fstep(fA[0]);
    if (rem > 1) fstep(fA[1]);
    if (rem > 2) fstep(fA[2]);
    if (rem > 3) fstep(fA[3]);
    if (rem > 4) fstep(fB[0]);
    if (rem > 5) fstep(fB[1]);
    if (rem > 6) fstep(fB[2]);
    {
      float alpha = (float)CE * 0.693147180559945f + __logf(p);  // p==0 -> -inf
      float v = alpha + t_stop;
      // lanes 0-31 hold all 32 tags (dup in 32-63): xor set {1,2,4,8,16}
      float M2 = v;
      M2 = fmaxf(M2, __shfl_xor(M2, 1, 64));
      M2 = fmaxf(M2, __shfl_xor(M2, 2, 64));
      M2 = fmaxf(M2, __shfl_xor(M2, 4, 64));
      M2 = fmaxf(M2, __shfl_xor(M2, 8, 64));
      M2 = fmaxf(M2, __shfl_xor(M2, 16, 64));
      float e = __expf(v - M2);
      e += __shfl_xor(e, 1, 64);
      e += __shfl_xor(e, 2, 64);
      e += __shfl_xor(e, 4, 64);
      e += __shfl_xor(e, 8, 64);
      e += __shfl_xor(e, 16, 64);
      if (l == 0) out[b] = M2 + __logf(e);
    }
    return;
  }

  // ========================= viterbi =========================
  {
    float tT[16];
    unsigned tgb[16];                         // 1u << source-tag (ffs argmax)
#pragma unroll
    for (int m = 0; m < 16; ++m) {
      int j = srcbase | (t0 ^ m);
      tT[m]  = trans[i * TT + j];
      tgb[m] = 1u << j;
    }

    float sc = (i == 29) ? 0.0f : -10000.0f;
    float* outp = out + POFF + (size_t)b * TT + i;

    auto vstep = [&](float& best, int& ptr) {
      float z = swap16(sc, hi16);
      float x = hiHalf ? z : sc;
      float r7  = dppx<DPP_RHMIR>(x);
      float r8  = dppx<DPP_ROR8>(x);
      float r15 = dppx<DPP_RMIR>(x);
      float vv[16];
      vv[0]  = x + tT[0];
      vv[1]  = dppx<DPP_QX1>(x) + tT[1];
      vv[2]  = dppx<DPP_QX2>(x) + tT[2];
      vv[3]  = dppx<DPP_QX3>(x) + tT[3];
      vv[4]  = dppx<DPP_QX3>(r7) + tT[4];
      vv[5]  = dppx<DPP_QX2>(r7) + tT[5];
      vv[6]  = dppx<DPP_QX1>(r7) + tT[6];
      vv[7]  = r7 + tT[7];
      vv[8]  = r8 + tT[8];
      vv[9]  = dppx<DPP_QX1>(r8) + tT[9];
      vv[10] = dppx<DPP_QX2>(r8) + tT[10];
      vv[11] = dppx<DPP_QX3>(r8) + tT[11];
      vv[12] = dppx<DPP_QX3>(r15) + tT[12];
      vv[13] = dppx<DPP_QX2>(r15) + tT[13];
      vv[14] = dppx<DPP_QX1>(r15) + tT[14];
      vv[15] = r15 + tT[15];
      // exact max (3-ary nesting -> v_max3_f32)
      float g0 = fmaxf(fmaxf(vv[0], vv[1]), vv[2]);
      float g1 = fmaxf(fmaxf(vv[3], vv[4]), vv[5]);
      float g2 = fmaxf(fmaxf(vv[6], vv[7]), vv[8]);
      float g3 = fmaxf(fmaxf(vv[9], vv[10]), vv[11]);
      float g4 = fmaxf(fmaxf(vv[12], vv[13]), vv[14]);
      float h0 = fmaxf(fmaxf(g0, g1), g2);
      float h1 = fmaxf(fmaxf(g3, g4), vv[15]);
      float mxp = fmaxf(h0, h1);
      float mx  = fmaxf(mxp, swap32(mxp, hiHalf));  // global over 32 sources
      // leftmost argmax: OR of tag-bits among exact-max matches, then ffs
      unsigned msk = 0u;
#pragma unroll
      for (int m = 0; m < 16; ++m) msk |= (vv[m] == mx) ? tgb[m] : 0u;
      msk |= uswap32(msk, hiHalf);
      best = mx;
      ptr  = __ffs(msk) - 1;
    };

#pragma unroll 1
    for (int s = 0; s < lim8; s += 8) {
#pragma unroll
      for (int u2 = 0; u2 < 4; ++u2) {
        float best; int ptr;
        vstep(best, ptr);
        if (l < 32) outp[(size_t)(s + u2) * STEP] = (float)ptr;
        sc = best + fA[u2];                 // bit-exact vs numpy
      }
#pragma unroll
      for (int u2 = 0; u2 < 4; ++u2)
        fA[u2] = fbase[(size_t)((s + 8 + u2) & (SS - 1)) * STEP];
#pragma unroll
      for (int u2 = 0; u2 < 4; ++u2) {
        float best; int ptr;
        vstep(best, ptr);
        if (l < 32) outp[(size_t)(s + 4 + u2) * STEP] = (float)ptr;
        sc = best + fB[u2];
      }
#pragma unroll
      for (int u2 = 0; u2 < 4; ++u2)
        fB[u2] = fbase[(size_t)((s + 12 + u2) & (SS - 1)) * STEP];
    }
    // tail steps lim8..len-1 (data already in fA/fB)
    {
      float tf[7] = {fA[0], fA[1], fA[2], fA[3], fB[0], fB[1], fB[2]};
#pragma unroll 1
      for (int k2 = 0; k2 < rem; ++k2) {
        float best; int ptr;
        vstep(best, ptr);
        if (l < 32) outp[(size_t)(lim8 + k2) * STEP] = (float)ptr;
        sc = best + tf[k2];
      }
    }
    {
      // frozen scores -> constant ptr rows: compute once, store-only loop
      float tb; int tp;
      vstep(tb, tp);
      float tj = (float)tp;
#pragma unroll 1
      for (int s2 = len; s2 < SS; ++s2)
        if (l < 32) outp[(size_t)s2 * STEP] = tj;

      float w = sc + t_stop;
      w = fmaxf(w, __shfl_xor(w, 1, 64));
      w = fmaxf(w, __shfl_xor(w, 2, 64));
      w = fmaxf(w, __shfl_xor(w, 4, 64));
      w = fmaxf(w, __shfl_xor(w, 8, 64));
      w = fmaxf(w, __shfl_xor(w, 16, 64));
      if (l == 0) out[BB + b] = w;
    }
  }
}

extern "C" void kernel_launch(void* const* d_in, const int* in_sizes, int n_in,
                              void* d_out, int out_size, void* d_ws, size_t ws_size,
                              hipStream_t stream) {
  const float* feats = (const float*)d_in[0];
  const float* msk   = (const float*)d_in[1];
  const float* trans = (const float*)d_in[2];
  float* out = (float*)d_out;
  (void)in_sizes; (void)n_in; (void)out_size; (void)d_ws; (void)ws_size;
  crf11_kernel<<<dim3(BB), dim3(128), 0, stream>>>(feats, msk, trans, out);
}